// Round 7
// baseline (299.853 us; speedup 1.0000x reference)
//
#include <hip/hip_runtime.h>

#define TT    2000
#define NG    4000
#define WARM  365
#define LENF  15
#define NPHY  12
#define BLK   15                  // timesteps per staged block
#define SLOTW 64                  // dwords per step in LDS (48 used + 16 pad)
#define SLOTD (BLK * SLOTW)       // 960 dwords per block slot
#define NBLK  134                 // 134*15 = 2010 steps (covers TT, stores gated)

typedef const float __attribute__((address_space(1)))* gptr_t;
typedef float __attribute__((address_space(3)))* lptr_t;

// Quad-wide sum via DPP (VALU-only; no LDS pipe).
__device__ __forceinline__ float quad_sum(float x) {
    int a = __builtin_amdgcn_update_dpp(0, __float_as_int(x), 0xB1, 0xF, 0xF, true);
    float s = x + __int_as_float(a);
    int b = __builtin_amdgcn_update_dpp(0, __float_as_int(s), 0x4E, 0xF, 0xF, true);
    return s + __int_as_float(b);
}

// One workgroup = one wave = 16 grid cells (4 multiplier lanes each).
// SKEWED software pipeline over 15-step blocks: per iteration i we run
//   snow(block i) | soil(block i-1) | response+conv(block i-2)
// The three chains touch different blocks' data, so the scheduler CANNOT
// re-serialize them into one long per-step chain (round-6 failure mode);
// each chain's dependency stalls are filled by the other two chains.
__global__ __launch_bounds__(64, 1) void hbv_route_kernel(
    const float* __restrict__ xphy,   // [T, G, 3]
    const float* __restrict__ prm,    // [1, G, 50]
    float* __restrict__ out)          // [T-WARM, G]
{
    __shared__ float lds[4 * SLOTD];  // 15360 B

    const int lane = threadIdx.x;     // 0..63
    const int g0   = blockIdx.x * 16; // 250 blocks * 16 g = 4000
    const int g    = g0 + (lane >> 2);
    const int m    = lane & 3;

    const float* pg = prm + (size_t)g * (NPHY * 4 + 2);

    const float lb[NPHY] = {1.0f, 50.0f, 0.05f, 0.01f, 0.001f, 0.2f, 0.0f, 0.0f, -2.5f, 0.5f, 0.0f, 0.0f};
    const float ub[NPHY] = {6.0f, 1000.0f, 0.9f, 0.5f, 0.2f, 1.0f, 10.0f, 100.0f, 2.5f, 10.0f, 0.1f, 0.2f};
    float ph[NPHY];
    #pragma unroll
    for (int i = 0; i < NPHY; ++i)
        ph[i] = lb[i] + pg[i * 4 + m] * (ub[i] - lb[i]);

    const float beta = ph[0], fc = ph[1], k0 = ph[2], k1 = ph[3], k2 = ph[4],
                lp = ph[5], perc = ph[6], uzl = ph[7], ttp = ph[8],
                cfmax = ph[9], cfr = ph[10], cwh = ph[11];
    const float rfc   = 1.0f / fc;
    const float rlpfc = 1.0f / (lp * fc);
    const float cfrcf = cfr * cfmax;

    // Routing weights (gammaln / th^aa cancel under normalization).
    // 0.25 (mean over NMUL) folded into w.
    const float aa  = fmaxf(pg[48] * 2.9f, 0.0f) + 0.1f;
    const float th  = fmaxf(pg[49] * 6.5f, 0.0f) + 0.5f;
    const float rth = 1.0f / th;
    const float LOG2E = 1.4426950408889634f;
    float w[LENF];
    float wsum = 0.0f;
    #pragma unroll
    for (int k = 0; k < LENF; ++k) {
        const float tg = (float)k + 0.5f;
        const float e = (aa - 1.0f) * __builtin_log2f(tg) - tg * rth * LOG2E;
        w[k] = __builtin_amdgcn_exp2f(e);
        wsum += w[k];
    }
    const float rw = 0.25f / wsum;
    #pragma unroll
    for (int k = 0; k < LENF; ++k) w[k] *= rw;

    // Per-chain recurrent states
    float snowpack = 0.001f, meltwater = 0.001f;   // stage 1
    float sm = 0.001f;                              // stage 2
    float suz = 0.001f, slz = 0.001f;               // stage 3

    float acc[LENF];
    #pragma unroll
    for (int k = 0; k < LENF; ++k) acc[k] = 0.0f;

    // Ping-pong inter-stage buffers (static-indexed; live across iterations
    // by construction -> compiler cannot collapse the skew).
    float rtE[BLK], uuE[BLK], evE[BLK], rexE[BLK];
    float rtO[BLK], uuO[BLK], evO[BLK], rexO[BLK];

    const int loffd = (lane < 48 ? lane : 47);

    auto issue_blk = [&](int b) {
        const int slot = b & 3;
        const int t0 = b * BLK;
        #pragma unroll
        for (int c = 0; c < BLK; ++c) {
            int t = t0 + c;
            if (t > TT - 1) t = TT - 1;
            const float* gsrc = xphy + (size_t)t * (3 * NG) + g0 * 3 + loffd;
            float* ldst = &lds[slot * SLOTD + c * SLOTW];
            __builtin_amdgcn_global_load_lds((gptr_t)gsrc, (lptr_t)ldst, 4, 0, 0);
        }
    };

    // Stage 1: snow recurrence for block i. LDS -> regs, produce rt/uu/ev.
    auto snow_stage = [&](int i, float (&rt)[BLK], float (&uu)[BLK], float (&ev)[BLK]) {
        const float* lbase = &lds[(i & 3) * SLOTD + (lane >> 2) * 3];
        float P[BLK], Tm[BLK];
        #pragma unroll
        for (int j = 0; j < BLK; ++j) {
            P[j]  = lbase[j * SLOTW + 0];
            Tm[j] = lbase[j * SLOTW + 1];
            ev[j] = lbase[j * SLOTW + 2];
        }
        #pragma unroll
        for (int j = 0; j < BLK; ++j) {
            const float dT      = Tm[j] - ttp;
            const float rain    = (Tm[j] >= ttp) ? P[j] : 0.0f;
            const float snow    = P[j] - rain;
            const float meltcap = cfmax * fmaxf(dT, 0.0f);
            const float refcap  = cfrcf * fmaxf(-dT, 0.0f);

            snowpack += snow;
            const float melt = fminf(meltcap, snowpack);
            meltwater += melt;
            snowpack  -= melt;
            const float refreeze = fminf(refcap, meltwater);
            meltwater -= refreeze;
            snowpack  += refreeze;
            const float tosoil = fmaxf(fmaf(-cwh, snowpack, meltwater), 0.0f);
            meltwater -= tosoil;

            rt[j] = rain + tosoil;
            uu[j] = fminf(ev[j] * rlpfc, 1.0f);
        }
    };

    // Stage 2: soil-moisture recurrence for block i-1.
    auto soil_stage = [&](const float (&rt)[BLK], const float (&uu)[BLK],
                          const float (&ev)[BLK], float (&rex)[BLK]) {
        #pragma unroll
        for (int j = 0; j < BLK; ++j) {
            const float sw    = __builtin_amdgcn_exp2f(beta * __builtin_amdgcn_logf(sm * rfc));
            const float smprt = sm + rt[j];
            const float sm1   = fmaf(-rt[j], sw, smprt);     // sm + rt*(1-sw)
            const float sm2   = fminf(sm1, fc);
            const float etact = fminf(sm2 * uu[j], ev[j]);
            sm = fmaxf(sm2 - etact, 1e-5f);
            rex[j] = fmaf(rt[j], sw, sm1 - sm2);             // recharge + excess
        }
    };

    // Stage 3: response recurrence + quad mean + conv + stores for block bb.
    auto resp_stage = [&](int bb, const float (&rex)[BLK]) {
        const int t0 = bb * BLK;
        float o0 = 0.0f, o1 = 0.0f, o2 = 0.0f, o3 = 0.0f;
        #pragma unroll
        for (int j = 0; j < BLK; ++j) {
            const float suz1 = suz + rex[j];
            const float prc  = fminf(suz1, perc);
            const float suzA = suz1 - prc;
            const float tq   = fmaxf(suzA - uzl, 0.0f);
            const float q0   = k0 * tq;
            const float suzB = suzA - q0;
            const float q1   = k1 * suzB;
            suz = suzB - q1;
            const float slz1 = slz + prc;
            const float q2   = k2 * slz1;
            slz = slz1 - q2;

            const float q = quad_sum(q0 + q1 + q2);  // *0.25 folded into w

            const float o = acc[j] + w[0] * q;
            acc[j] = 0.0f;
            #pragma unroll
            for (int k = 1; k < LENF; ++k) {
                int idx = j + k;
                if (idx >= LENF) idx -= LENF;
                acc[idx] += w[k] * q;
            }

            const bool sel = ((j & 3) == m);
            if ((j >> 2) == 0)      o0 = sel ? o : o0;
            else if ((j >> 2) == 1) o1 = sel ? o : o1;
            else if ((j >> 2) == 2) o2 = sel ? o : o2;
            else                    o3 = sel ? o : o3;
        }
        #pragma unroll
        for (int k = 0; k < 4; ++k) {
            const int j = k * 4 + m;
            const int t = t0 + j;
            const float ov = (k == 0) ? o0 : (k == 1) ? o1 : (k == 2) ? o2 : o3;
            if (j < BLK && t >= WARM && t < TT)
                out[(size_t)(t - WARM) * NG + g] = ov;
        }
    };

    issue_blk(0);
    issue_blk(1);

    // ---- prologue: i = 0 (even), i = 1 (odd) ----
    asm volatile("s_waitcnt vmcnt(15)" ::: "memory");
    issue_blk(2);
    snow_stage(0, rtE, uuE, evE);

    asm volatile("s_waitcnt vmcnt(15)" ::: "memory");
    issue_blk(3);
    snow_stage(1, rtO, uuO, evO);
    soil_stage(rtE, uuE, evE, rexO);                 // block 0

    // ---- main loop: i = 2..133 (even/odd pairs) ----
    for (int ii = 2; ii < NBLK; ii += 2) {
        // even iteration i = ii
        asm volatile("s_waitcnt vmcnt(15)" ::: "memory");
        issue_blk(ii + 2);
        snow_stage(ii, rtE, uuE, evE);               // block ii
        soil_stage(rtO, uuO, evO, rexE);             // block ii-1
        resp_stage(ii - 2, rexO);                    // block ii-2

        // odd iteration i = ii+1
        asm volatile("s_waitcnt vmcnt(15)" ::: "memory");
        issue_blk(ii + 3);
        snow_stage(ii + 1, rtO, uuO, evO);           // block ii+1
        soil_stage(rtE, uuE, evE, rexO);             // block ii
        resp_stage(ii - 1, rexE);                    // block ii-1
    }

    // ---- epilogue: i = 134 (even), i = 135 (odd) ----
    soil_stage(rtO, uuO, evO, rexE);                 // block 133
    resp_stage(NBLK - 2, rexO);                      // block 132
    resp_stage(NBLK - 1, rexE);                      // block 133
}

extern "C" void kernel_launch(void* const* d_in, const int* in_sizes, int n_in,
                              void* d_out, int out_size, void* d_ws, size_t ws_size,
                              hipStream_t stream) {
    const float* xphy = (const float*)d_in[0];   // [2000, 4000, 3]
    const float* prm  = (const float*)d_in[1];   // [1, 4000, 50]
    float* out = (float*)d_out;                  // [1635, 4000, 1]

    hbv_route_kernel<<<NG / 16, 64, 0, stream>>>(xphy, prm, out);
}

// Round 8
// 180.810 us; speedup vs baseline: 1.6584x; 1.6584x over previous
//
#include <hip/hip_runtime.h>

#define TT    2000
#define NG    4000
#define WARM  365
#define LENF  15
#define NPHY  12
#define BLK   15                  // timesteps per staged block
#define SLOTW 64                  // dwords per step in stage LDS (48 used + pad)
#define SLOTD (BLK * SLOTW)       // 960 dwords per stage slot
#define NBLK  134                 // 134*15 = 2010 steps (covers TT, stores gated)
#define RING  (BLK * 64)          // 960 dwords per handoff ring slot

typedef const float __attribute__((address_space(1)))* gptr_t;
typedef float __attribute__((address_space(3)))* lptr_t;

// Quad-wide sum via DPP (VALU-only; no LDS pipe).
__device__ __forceinline__ float quad_sum(float x) {
    int a = __builtin_amdgcn_update_dpp(0, __float_as_int(x), 0xB1, 0xF, 0xF, true);
    float s = x + __int_as_float(a);
    int b = __builtin_amdgcn_update_dpp(0, __float_as_int(s), 0x4E, 0xF, 0xF, true);
    return s + __int_as_float(b);
}

// Raw barrier: wait own ds ops, then barrier. NO vmcnt drain — wave0's
// global_load_lds prefetch queue must survive (T4 counted-vmcnt pattern).
#define WG_BARRIER() asm volatile("s_waitcnt lgkmcnt(0)\n\ts_barrier" ::: "memory")

// Wave-specialized pipeline: 4 waves / workgroup on 4 SIMDs of one CU.
//   wave0: stage loads + snow chain (block i)      -> s_rt ring
//   wave1: soil-moisture chain      (block i-1)    -> s_rex ring
//   wave2: response chain + quad mean (block i-2)  -> s_q ring
//   wave3: 15-tap routing conv + stores (block i-3)
// Rationale: 1 wave/CU caps VALUBusy at 25% (1 of 4 SIMDs); the three
// recurrences are independent chains coupled only by forward handoffs, so
// they can run on separate SIMDs, skewed one block apart.
__global__ __launch_bounds__(256, 1) void hbv_pipe_kernel(
    const float* __restrict__ xphy,   // [T, G, 3]
    const float* __restrict__ prm,    // [1, G, 50]
    float* __restrict__ out)          // [T-WARM, G]
{
    __shared__ float s_stage[4 * SLOTD];  // 15360 B input stage ring
    __shared__ float s_rt [2 * RING];     // snow -> soil
    __shared__ float s_rex[2 * RING];     // soil -> response
    __shared__ float s_q  [2 * RING];     // response -> conv

    const int lane = threadIdx.x & 63;
    const int wid  = threadIdx.x >> 6;    // 0..3
    const int g0   = blockIdx.x * 16;     // 250 workgroups * 16 cells
    const int g    = g0 + (lane >> 2);
    const int m    = lane & 3;

    const float* pg = prm + (size_t)g * (NPHY * 4 + 2);

    const float lb[NPHY] = {1.0f, 50.0f, 0.05f, 0.01f, 0.001f, 0.2f, 0.0f, 0.0f, -2.5f, 0.5f, 0.0f, 0.0f};
    const float ub[NPHY] = {6.0f, 1000.0f, 0.9f, 0.5f, 0.2f, 1.0f, 10.0f, 100.0f, 2.5f, 10.0f, 0.1f, 0.2f};
    float ph[NPHY];
    #pragma unroll
    for (int i = 0; i < NPHY; ++i)
        ph[i] = lb[i] + pg[i * 4 + m] * (ub[i] - lb[i]);

    const float beta = ph[0], fc = ph[1], k0 = ph[2], k1 = ph[3], k2 = ph[4],
                lp = ph[5], perc = ph[6], uzl = ph[7], ttp = ph[8],
                cfmax = ph[9], cfr = ph[10], cwh = ph[11];
    const float rfc    = 1.0f / fc;
    const float rlpfc  = 1.0f / (lp * fc);
    const float cfrcf  = cfr * cfmax;
    const float blfc   = beta * __builtin_amdgcn_logf(rfc);  // beta*log2(1/fc)
    const float onemk1 = 1.0f - k1;
    const float onemk2 = 1.0f - k2;

    // Routing weights (gammaln / th^aa cancel under normalization);
    // 0.25 multiplier mean folded in.
    const float aa  = fmaxf(pg[48] * 2.9f, 0.0f) + 0.1f;
    const float th  = fmaxf(pg[49] * 6.5f, 0.0f) + 0.5f;
    const float rth = 1.0f / th;
    const float LOG2E = 1.4426950408889634f;
    float w[LENF];
    float wsum = 0.0f;
    #pragma unroll
    for (int k = 0; k < LENF; ++k) {
        const float tg = (float)k + 0.5f;
        const float e = (aa - 1.0f) * __builtin_log2f(tg) - tg * rth * LOG2E;
        w[k] = __builtin_amdgcn_exp2f(e);
        wsum += w[k];
    }
    const float rw = 0.25f / wsum;
    #pragma unroll
    for (int k = 0; k < LENF; ++k) w[k] *= rw;

    // Per-wave persistent states
    float snowpack = 0.001f, meltwater = 0.001f;   // wave0
    float sm = 0.001f;                             // wave1
    float suz = 0.001f, slz = 0.001f;              // wave2
    float qh[2 * BLK - 1];                         // wave3: q history (static idx)
    #pragma unroll
    for (int d = 0; d < 2 * BLK - 1; ++d) qh[d] = 0.0f;

    const int loffd = (lane < 48 ? lane : 47);

    auto issue_blk = [&](int b) {
        const int slot = b & 3;
        const int t0 = b * BLK;
        #pragma unroll
        for (int c = 0; c < BLK; ++c) {
            int t = t0 + c;
            if (t > TT - 1) t = TT - 1;
            const float* gsrc = xphy + (size_t)t * (3 * NG) + g0 * 3 + loffd;
            float* ldst = &s_stage[slot * SLOTD + c * SLOTW];
            __builtin_amdgcn_global_load_lds((gptr_t)gsrc, (lptr_t)ldst, 4, 0, 0);
        }
    };

    if (wid == 0) { issue_blk(0); issue_blk(1); }

    for (int i = 0; i <= NBLK + 2; ++i) {
        if (wid == 0) {
            // ---- stage + snow chain, block i ----
            if (i < NBLK) {
                asm volatile("s_waitcnt vmcnt(15)" ::: "memory");  // block i landed
                issue_blk(i + 2);                                  // clamped past end
                const float* sb = &s_stage[(i & 3) * SLOTD + (lane >> 2) * 3];
                float P[BLK], Tm[BLK];
                #pragma unroll
                for (int j = 0; j < BLK; ++j) { P[j] = sb[j * SLOTW]; Tm[j] = sb[j * SLOTW + 1]; }
                float* rtw = &s_rt[(i & 1) * RING + lane];
                #pragma unroll
                for (int j = 0; j < BLK; ++j) {
                    const float dT      = Tm[j] - ttp;
                    const float rain    = (Tm[j] >= ttp) ? P[j] : 0.0f;
                    const float snow    = P[j] - rain;
                    const float meltcap = cfmax * fmaxf(dT, 0.0f);
                    const float refcap  = cfrcf * fmaxf(-dT, 0.0f);
                    snowpack += snow;
                    const float melt = fminf(meltcap, snowpack);
                    meltwater += melt;
                    snowpack  -= melt;
                    const float refreeze = fminf(refcap, meltwater);
                    meltwater -= refreeze;
                    snowpack  += refreeze;
                    const float tosoil = fmaxf(fmaf(-cwh, snowpack, meltwater), 0.0f);
                    meltwater -= tosoil;
                    rtw[j * 64] = rain + tosoil;
                }
            }
        } else if (wid == 1) {
            // ---- soil-moisture chain, block i-1 ----
            const int b = i - 1;
            if (b >= 0 && b < NBLK) {
                const float* sb  = &s_stage[(b & 3) * SLOTD + (lane >> 2) * 3];
                const float* rtr = &s_rt[(b & 1) * RING + lane];
                float rt[BLK], ev[BLK], uum1[BLK];
                #pragma unroll
                for (int j = 0; j < BLK; ++j) { rt[j] = rtr[j * 64]; ev[j] = sb[j * SLOTW + 2]; }
                #pragma unroll
                for (int j = 0; j < BLK; ++j)
                    uum1[j] = fmaxf(fmaf(-ev[j], rlpfc, 1.0f), 0.0f);   // 1 - evap factor
                float* rexw = &s_rex[(b & 1) * RING + lane];
                #pragma unroll
                for (int j = 0; j < BLK; ++j) {
                    // sw = (sm/fc)^beta = exp2(beta*log2(sm) + beta*log2(1/fc))
                    const float sw    = __builtin_amdgcn_exp2f(fmaf(beta, __builtin_amdgcn_logf(sm), blfc));
                    const float smprt = sm + rt[j];
                    const float sm1   = fmaf(-rt[j], sw, smprt);   // sm + rt*(1-sw)
                    const float sm2   = fminf(sm1, fc);
                    // sm2 - min(sm2, sm2*uu, ev) = max(sm2*(1-uu), sm2-ev)
                    const float av = sm2 * uum1[j];
                    const float cv = sm2 - ev[j];
                    sm = fmaxf(fmaxf(av, cv), 1e-5f);
                    rexw[j * 64] = fmaf(rt[j], sw, sm1 - sm2);     // recharge + excess
                }
            }
        } else if (wid == 2) {
            // ---- response chain + quad mean, block i-2 ----
            const int b = i - 2;
            if (b >= 0 && b < NBLK) {
                const float* rexr = &s_rex[(b & 1) * RING + lane];
                float rex[BLK];
                #pragma unroll
                for (int j = 0; j < BLK; ++j) rex[j] = rexr[j * 64];
                float* qw = &s_q[(b & 1) * RING + lane];
                #pragma unroll
                for (int j = 0; j < BLK; ++j) {
                    const float suz1 = suz + rex[j];
                    const float prc  = fminf(suz1, perc);
                    const float suzA = suz1 - prc;
                    const float tq   = fmaxf(suzA - uzl, 0.0f);
                    const float q0   = k0 * tq;
                    const float suzB = fmaf(-k0, tq, suzA);
                    const float q1   = k1 * suzB;
                    suz = suzB * onemk1;
                    const float slz1 = slz + prc;
                    const float q2   = k2 * slz1;
                    slz = slz1 * onemk2;
                    qw[j * 64] = quad_sum(q0 + q1 + q2);   // *0.25 folded into w
                }
            }
        } else {
            // ---- 15-tap routing conv (gather form) + stores, block i-3 ----
            const int b = i - 3;
            if (b >= 0 && b < NBLK) {
                const int t0 = b * BLK;
                const float* qr = &s_q[(b & 1) * RING + lane];
                #pragma unroll
                for (int j = 0; j < BLK; ++j) qh[14 + j] = qr[j * 64];
                float o0 = 0.0f, o1 = 0.0f, o2 = 0.0f, o3 = 0.0f;
                #pragma unroll
                for (int j = 0; j < BLK; ++j) {
                    float o = w[0] * qh[14 + j];
                    #pragma unroll
                    for (int k = 1; k < LENF; ++k)
                        o = fmaf(w[k], qh[14 + j - k], o);
                    const bool sel = ((j & 3) == m);
                    if ((j >> 2) == 0)      o0 = sel ? o : o0;
                    else if ((j >> 2) == 1) o1 = sel ? o : o1;
                    else if ((j >> 2) == 2) o2 = sel ? o : o2;
                    else                    o3 = sel ? o : o3;
                }
                #pragma unroll
                for (int d = 0; d < 14; ++d) qh[d] = qh[d + 15];   // static shift
                #pragma unroll
                for (int k = 0; k < 4; ++k) {
                    const int j = k * 4 + m;
                    const int t = t0 + j;
                    const float ov = (k == 0) ? o0 : (k == 1) ? o1 : (k == 2) ? o2 : o3;
                    if (j < BLK && t >= WARM && t < TT)
                        out[(size_t)(t - WARM) * NG + g] = ov;
                }
            }
        }
        WG_BARRIER();
    }
    // drain wave0's leftover in-flight LDS-writing loads before endpgm
    if (wid == 0) asm volatile("s_waitcnt vmcnt(0)" ::: "memory");
}

extern "C" void kernel_launch(void* const* d_in, const int* in_sizes, int n_in,
                              void* d_out, int out_size, void* d_ws, size_t ws_size,
                              hipStream_t stream) {
    const float* xphy = (const float*)d_in[0];   // [2000, 4000, 3]
    const float* prm  = (const float*)d_in[1];   // [1, 4000, 50]
    float* out = (float*)d_out;                  // [1635, 4000, 1]

    hbv_pipe_kernel<<<NG / 16, 256, 0, stream>>>(xphy, prm, out);
}

// Round 9
// 156.333 us; speedup vs baseline: 1.9180x; 1.1566x over previous
//
#include <hip/hip_runtime.h>

#define TT    2000
#define NG    4000
#define WARM  365
#define LENF  15
#define NPHY  12
#define BLK   30                  // timesteps per staged block
#define SLOTW 64                  // dwords per step in stage LDS (48 used + pad)
#define SLOTD (BLK * SLOTW)       // 1920 dwords per stage slot
#define NBLK  67                  // 67*30 = 2010 steps (covers TT, stores gated)
#define RING  (BLK * 64)          // 1920 dwords per handoff ring slot

typedef const float __attribute__((address_space(1)))* gptr_t;
typedef float __attribute__((address_space(3)))* lptr_t;

// Quad-wide sum via DPP (VALU-only; no LDS pipe).
__device__ __forceinline__ float quad_sum(float x) {
    int a = __builtin_amdgcn_update_dpp(0, __float_as_int(x), 0xB1, 0xF, 0xF, true);
    float s = x + __int_as_float(a);
    int b = __builtin_amdgcn_update_dpp(0, __float_as_int(s), 0x4E, 0xF, 0xF, true);
    return s + __int_as_float(b);
}

// Raw barrier: wait own ds ops, then barrier. NO vmcnt drain — wave0's
// global_load_lds prefetch queue must survive (T4 counted-vmcnt pattern).
#define WG_BARRIER() asm volatile("s_waitcnt lgkmcnt(0)\n\ts_barrier" ::: "memory")

// Wave-specialized pipeline: 4 waves / workgroup on 4 SIMDs of one CU.
//   wave0: stage loads + snow chain (block i)      -> s_rt ring
//   wave1: soil-moisture chain      (block i-1)    -> s_rex ring
//   wave2: response chain + quad mean (block i-2)  -> s_q ring
//   wave3: 15-tap routing conv + stores (block i-3)
// BLK=30: halves the number of barrier iterations vs BLK=15 to amortize the
// ~2500 cyc/iter fixed sync+handoff-latency overhead measured in r8.
__global__ __launch_bounds__(256, 1) void hbv_pipe_kernel(
    const float* __restrict__ xphy,   // [T, G, 3]
    const float* __restrict__ prm,    // [1, G, 50]
    float* __restrict__ out)          // [T-WARM, G]
{
    __shared__ float s_stage[4 * SLOTD];  // 30720 B input stage ring
    __shared__ float s_rt [2 * RING];     // snow -> soil      (15360 B)
    __shared__ float s_rex[2 * RING];     // soil -> response  (15360 B)
    __shared__ float s_q  [2 * RING];     // response -> conv  (15360 B)

    const int lane = threadIdx.x & 63;
    const int wid  = threadIdx.x >> 6;    // 0..3
    const int g0   = blockIdx.x * 16;     // 250 workgroups * 16 cells
    const int g    = g0 + (lane >> 2);
    const int m    = lane & 3;

    const float* pg = prm + (size_t)g * (NPHY * 4 + 2);

    const float lb[NPHY] = {1.0f, 50.0f, 0.05f, 0.01f, 0.001f, 0.2f, 0.0f, 0.0f, -2.5f, 0.5f, 0.0f, 0.0f};
    const float ub[NPHY] = {6.0f, 1000.0f, 0.9f, 0.5f, 0.2f, 1.0f, 10.0f, 100.0f, 2.5f, 10.0f, 0.1f, 0.2f};
    float ph[NPHY];
    #pragma unroll
    for (int i = 0; i < NPHY; ++i)
        ph[i] = lb[i] + pg[i * 4 + m] * (ub[i] - lb[i]);

    const float beta = ph[0], fc = ph[1], k0 = ph[2], k1 = ph[3], k2 = ph[4],
                lp = ph[5], perc = ph[6], uzl = ph[7], ttp = ph[8],
                cfmax = ph[9], cfr = ph[10], cwh = ph[11];
    const float rfc    = 1.0f / fc;
    const float rlpfc  = 1.0f / (lp * fc);
    const float cfrcf  = cfr * cfmax;
    const float blfc   = beta * __builtin_amdgcn_logf(rfc);  // beta*log2(1/fc)
    const float onemk1 = 1.0f - k1;
    const float onemk2 = 1.0f - k2;

    // Routing weights (gammaln / th^aa cancel under normalization);
    // 0.25 multiplier mean folded in.
    const float aa  = fmaxf(pg[48] * 2.9f, 0.0f) + 0.1f;
    const float th  = fmaxf(pg[49] * 6.5f, 0.0f) + 0.5f;
    const float rth = 1.0f / th;
    const float LOG2E = 1.4426950408889634f;
    float w[LENF];
    float wsum = 0.0f;
    #pragma unroll
    for (int k = 0; k < LENF; ++k) {
        const float tg = (float)k + 0.5f;
        const float e = (aa - 1.0f) * __builtin_log2f(tg) - tg * rth * LOG2E;
        w[k] = __builtin_amdgcn_exp2f(e);
        wsum += w[k];
    }
    const float rw = 0.25f / wsum;
    #pragma unroll
    for (int k = 0; k < LENF; ++k) w[k] *= rw;

    // Per-wave persistent states
    float snowpack = 0.001f, meltwater = 0.001f;   // wave0
    float sm = 0.001f;                             // wave1
    float suz = 0.001f, slz = 0.001f;              // wave2
    float qh[BLK + LENF - 1];                      // wave3: q history (static idx)
    #pragma unroll
    for (int d = 0; d < BLK + LENF - 1; ++d) qh[d] = 0.0f;

    const int loffd = (lane < 48 ? lane : 47);

    auto issue_blk = [&](int b) {
        const int slot = b & 3;
        const int t0 = b * BLK;
        #pragma unroll
        for (int c = 0; c < BLK; ++c) {
            int t = t0 + c;
            if (t > TT - 1) t = TT - 1;
            const float* gsrc = xphy + (size_t)t * (3 * NG) + g0 * 3 + loffd;
            float* ldst = &s_stage[slot * SLOTD + c * SLOTW];
            __builtin_amdgcn_global_load_lds((gptr_t)gsrc, (lptr_t)ldst, 4, 0, 0);
        }
    };

    if (wid == 0) { issue_blk(0); issue_blk(1); }

    for (int i = 0; i <= NBLK + 2; ++i) {
        if (wid == 0) {
            // ---- stage + snow chain, block i ----
            if (i < NBLK) {
                asm volatile("s_waitcnt vmcnt(30)" ::: "memory");  // block i landed
                issue_blk(i + 2);                                  // clamped past end
                const float* sb = &s_stage[(i & 3) * SLOTD + (lane >> 2) * 3];
                float P[BLK], Tm[BLK];
                #pragma unroll
                for (int j = 0; j < BLK; ++j) { P[j] = sb[j * SLOTW]; Tm[j] = sb[j * SLOTW + 1]; }
                float* rtw = &s_rt[(i & 1) * RING + lane];
                #pragma unroll
                for (int j = 0; j < BLK; ++j) {
                    const float dT      = Tm[j] - ttp;
                    const float rain    = (Tm[j] >= ttp) ? P[j] : 0.0f;
                    const float snow    = P[j] - rain;
                    const float meltcap = cfmax * fmaxf(dT, 0.0f);
                    const float refcap  = cfrcf * fmaxf(-dT, 0.0f);
                    snowpack += snow;
                    const float melt = fminf(meltcap, snowpack);
                    meltwater += melt;
                    snowpack  -= melt;
                    const float refreeze = fminf(refcap, meltwater);
                    meltwater -= refreeze;
                    snowpack  += refreeze;
                    const float tosoil = fmaxf(fmaf(-cwh, snowpack, meltwater), 0.0f);
                    meltwater -= tosoil;
                    rtw[j * 64] = rain + tosoil;
                }
            }
        } else if (wid == 1) {
            // ---- soil-moisture chain, block i-1 ----
            const int b = i - 1;
            if (b >= 0 && b < NBLK) {
                const float* sb  = &s_stage[(b & 3) * SLOTD + (lane >> 2) * 3];
                const float* rtr = &s_rt[(b & 1) * RING + lane];
                float rt[BLK], ev[BLK], uum1[BLK];
                #pragma unroll
                for (int j = 0; j < BLK; ++j) { rt[j] = rtr[j * 64]; ev[j] = sb[j * SLOTW + 2]; }
                #pragma unroll
                for (int j = 0; j < BLK; ++j)
                    uum1[j] = fmaxf(fmaf(-ev[j], rlpfc, 1.0f), 0.0f);   // 1 - evap factor
                float* rexw = &s_rex[(b & 1) * RING + lane];
                #pragma unroll
                for (int j = 0; j < BLK; ++j) {
                    // sw = (sm/fc)^beta = exp2(beta*log2(sm) + beta*log2(1/fc))
                    const float sw    = __builtin_amdgcn_exp2f(fmaf(beta, __builtin_amdgcn_logf(sm), blfc));
                    const float smprt = sm + rt[j];
                    const float sm1   = fmaf(-rt[j], sw, smprt);   // sm + rt*(1-sw)
                    const float sm2   = fminf(sm1, fc);
                    // sm2 - min(sm2, sm2*uu, ev) = max(sm2*(1-uu), sm2-ev)
                    const float av = sm2 * uum1[j];
                    const float cv = sm2 - ev[j];
                    sm = fmaxf(fmaxf(av, cv), 1e-5f);              // v_max3
                    rexw[j * 64] = fmaf(rt[j], sw, sm1 - sm2);     // recharge + excess
                }
            }
        } else if (wid == 2) {
            // ---- response chain + quad mean, block i-2 ----
            const int b = i - 2;
            if (b >= 0 && b < NBLK) {
                const float* rexr = &s_rex[(b & 1) * RING + lane];
                float rex[BLK];
                #pragma unroll
                for (int j = 0; j < BLK; ++j) rex[j] = rexr[j * 64];
                float* qw = &s_q[(b & 1) * RING + lane];
                #pragma unroll
                for (int j = 0; j < BLK; ++j) {
                    const float suz1 = suz + rex[j];
                    const float prc  = fminf(suz1, perc);
                    const float suzA = suz1 - prc;
                    const float tq   = fmaxf(suzA - uzl, 0.0f);
                    const float q0   = k0 * tq;
                    const float suzB = fmaf(-k0, tq, suzA);
                    const float q1   = k1 * suzB;
                    suz = suzB * onemk1;
                    const float slz1 = slz + prc;
                    const float q2   = k2 * slz1;
                    slz = slz1 * onemk2;
                    qw[j * 64] = quad_sum(q0 + q1 + q2);   // *0.25 folded into w
                }
            }
        } else {
            // ---- 15-tap routing conv (gather form) + stores, block i-3 ----
            const int b = i - 3;
            if (b >= 0 && b < NBLK) {
                const int t0 = b * BLK;
                const float* qr = &s_q[(b & 1) * RING + lane];
                #pragma unroll
                for (int j = 0; j < BLK; ++j) qh[LENF - 1 + j] = qr[j * 64];
                float ov[(BLK + 3) / 4];
                #pragma unroll
                for (int k = 0; k < (BLK + 3) / 4; ++k) ov[k] = 0.0f;
                #pragma unroll
                for (int j = 0; j < BLK; ++j) {
                    float o = w[0] * qh[LENF - 1 + j];
                    #pragma unroll
                    for (int k = 1; k < LENF; ++k)
                        o = fmaf(w[k], qh[LENF - 1 + j - k], o);
                    const bool sel = ((j & 3) == m);
                    ov[j >> 2] = sel ? o : ov[j >> 2];     // j>>2 compile-time
                }
                #pragma unroll
                for (int d = 0; d < LENF - 1; ++d) qh[d] = qh[d + BLK];   // static shift
                #pragma unroll
                for (int k = 0; k < (BLK + 3) / 4; ++k) {
                    const int j = k * 4 + m;
                    const int t = t0 + j;
                    if (j < BLK && t >= WARM && t < TT)
                        out[(size_t)(t - WARM) * NG + g] = ov[k];
                }
            }
        }
        WG_BARRIER();
    }
    // drain wave0's leftover in-flight LDS-writing loads before endpgm
    if (wid == 0) asm volatile("s_waitcnt vmcnt(0)" ::: "memory");
}

extern "C" void kernel_launch(void* const* d_in, const int* in_sizes, int n_in,
                              void* d_out, int out_size, void* d_ws, size_t ws_size,
                              hipStream_t stream) {
    const float* xphy = (const float*)d_in[0];   // [2000, 4000, 3]
    const float* prm  = (const float*)d_in[1];   // [1, 4000, 50]
    float* out = (float*)d_out;                  // [1635, 4000, 1]

    hbv_pipe_kernel<<<NG / 16, 256, 0, stream>>>(xphy, prm, out);
}

// Round 10
// 156.302 us; speedup vs baseline: 1.9184x; 1.0002x over previous
//
#include <hip/hip_runtime.h>

#define TT    2000
#define NG    4000
#define WARM  365
#define LENF  15
#define NPHY  12
#define BLK   30                  // timesteps per staged block
#define SLOTW 64                  // dwords per step in stage LDS (48 used + pad)
#define SLOTD (BLK * SLOTW)       // 1920 dwords per stage slot
#define NBLK  67                  // 67*30 = 2010 steps (covers TT, stores gated)
#define RING  (BLK * 64)          // 1920 dwords per handoff ring slot

typedef const float __attribute__((address_space(1)))* gptr_t;
typedef float __attribute__((address_space(3)))* lptr_t;

// Scheduling fence: nothing moves across (keeps batched ds_reads hoisted).
#define SCHED_FENCE() __builtin_amdgcn_sched_barrier(0)

// Quad-wide sum via DPP (VALU-only; no LDS pipe).
__device__ __forceinline__ float quad_sum(float x) {
    int a = __builtin_amdgcn_update_dpp(0, __float_as_int(x), 0xB1, 0xF, 0xF, true);
    float s = x + __int_as_float(a);
    int b = __builtin_amdgcn_update_dpp(0, __float_as_int(s), 0x4E, 0xF, 0xF, true);
    return s + __int_as_float(b);
}

// Raw barrier: wait own ds ops, then barrier. NO vmcnt drain — wave0's
// global_load_lds prefetch queue must survive (T4 counted-vmcnt pattern).
#define WG_BARRIER() asm volatile("s_waitcnt lgkmcnt(0)\n\ts_barrier" ::: "memory")

// Wave-specialized pipeline: 4 waves / workgroup on 4 SIMDs of one CU.
//   wave0: stage loads + snow chain (block i)      -> s_rt ring
//   wave1: soil-moisture chain      (block i-1)    -> s_rex ring
//   wave2: response chain + quad mean (block i-2)  -> s_q ring
//   wave3: 15-tap routing conv + stores (block i-3)
// r10: sched_barrier(0) fences pin the batched LDS-read hoists (r9's VGPR=88
// showed the compiler re-sank reads into the chains -> ~200 cyc/step).
__global__ __launch_bounds__(256, 1) void hbv_pipe_kernel(
    const float* __restrict__ xphy,   // [T, G, 3]
    const float* __restrict__ prm,    // [1, G, 50]
    float* __restrict__ out)          // [T-WARM, G]
{
    __shared__ float s_stage[4 * SLOTD];  // 30720 B input stage ring
    __shared__ float s_rt [2 * RING];     // snow -> soil      (15360 B)
    __shared__ float s_rex[2 * RING];     // soil -> response  (15360 B)
    __shared__ float s_q  [2 * RING];     // response -> conv  (15360 B)

    const int lane = threadIdx.x & 63;
    const int wid  = threadIdx.x >> 6;    // 0..3
    const int g0   = blockIdx.x * 16;     // 250 workgroups * 16 cells
    const int g    = g0 + (lane >> 2);
    const int m    = lane & 3;

    const float* pg = prm + (size_t)g * (NPHY * 4 + 2);

    const float lb[NPHY] = {1.0f, 50.0f, 0.05f, 0.01f, 0.001f, 0.2f, 0.0f, 0.0f, -2.5f, 0.5f, 0.0f, 0.0f};
    const float ub[NPHY] = {6.0f, 1000.0f, 0.9f, 0.5f, 0.2f, 1.0f, 10.0f, 100.0f, 2.5f, 10.0f, 0.1f, 0.2f};
    float ph[NPHY];
    #pragma unroll
    for (int i = 0; i < NPHY; ++i)
        ph[i] = lb[i] + pg[i * 4 + m] * (ub[i] - lb[i]);

    const float beta = ph[0], fc = ph[1], k0 = ph[2], k1 = ph[3], k2 = ph[4],
                lp = ph[5], perc = ph[6], uzl = ph[7], ttp = ph[8],
                cfmax = ph[9], cfr = ph[10], cwh = ph[11];
    const float rfc    = 1.0f / fc;
    const float rlpfc  = 1.0f / (lp * fc);
    const float cfrcf  = cfr * cfmax;
    const float blfc   = beta * __builtin_amdgcn_logf(rfc);  // beta*log2(1/fc)
    const float onemk1 = 1.0f - k1;
    const float onemk2 = 1.0f - k2;

    // Routing weights (gammaln / th^aa cancel under normalization);
    // 0.25 multiplier mean folded in.
    const float aa  = fmaxf(pg[48] * 2.9f, 0.0f) + 0.1f;
    const float th  = fmaxf(pg[49] * 6.5f, 0.0f) + 0.5f;
    const float rth = 1.0f / th;
    const float LOG2E = 1.4426950408889634f;
    float w[LENF];
    float wsum = 0.0f;
    #pragma unroll
    for (int k = 0; k < LENF; ++k) {
        const float tg = (float)k + 0.5f;
        const float e = (aa - 1.0f) * __builtin_log2f(tg) - tg * rth * LOG2E;
        w[k] = __builtin_amdgcn_exp2f(e);
        wsum += w[k];
    }
    const float rw = 0.25f / wsum;
    #pragma unroll
    for (int k = 0; k < LENF; ++k) w[k] *= rw;

    // Per-wave persistent states
    float snowpack = 0.001f, meltwater = 0.001f;   // wave0
    float sm = 0.001f;                             // wave1
    float suz = 0.001f, slz = 0.001f;              // wave2
    float qh[BLK + LENF - 1];                      // wave3: q history (static idx)
    #pragma unroll
    for (int d = 0; d < BLK + LENF - 1; ++d) qh[d] = 0.0f;

    const int loffd = (lane < 48 ? lane : 47);

    auto issue_blk = [&](int b) {
        const int slot = b & 3;
        const int t0 = b * BLK;
        #pragma unroll
        for (int c = 0; c < BLK; ++c) {
            int t = t0 + c;
            if (t > TT - 1) t = TT - 1;
            const float* gsrc = xphy + (size_t)t * (3 * NG) + g0 * 3 + loffd;
            float* ldst = &s_stage[slot * SLOTD + c * SLOTW];
            __builtin_amdgcn_global_load_lds((gptr_t)gsrc, (lptr_t)ldst, 4, 0, 0);
        }
    };

    if (wid == 0) { issue_blk(0); issue_blk(1); }

    for (int i = 0; i <= NBLK + 2; ++i) {
        if (wid == 0) {
            // ---- stage + snow chain, block i ----
            if (i < NBLK) {
                asm volatile("s_waitcnt vmcnt(30)" ::: "memory");  // block i landed
                issue_blk(i + 2);                                  // clamped past end
                const float* sb = &s_stage[(i & 3) * SLOTD + (lane >> 2) * 3];
                float P[BLK], Tm[BLK];
                SCHED_FENCE();
                #pragma unroll
                for (int j = 0; j < BLK; ++j) { P[j] = sb[j * SLOTW]; Tm[j] = sb[j * SLOTW + 1]; }
                SCHED_FENCE();   // reads stay hoisted; chain below runs on regs
                float* rtw = &s_rt[(i & 1) * RING + lane];
                #pragma unroll
                for (int j = 0; j < BLK; ++j) {
                    const float dT      = Tm[j] - ttp;
                    const float rain    = (Tm[j] >= ttp) ? P[j] : 0.0f;
                    const float snow    = P[j] - rain;
                    const float meltcap = cfmax * fmaxf(dT, 0.0f);
                    const float refcap  = cfrcf * fmaxf(-dT, 0.0f);
                    snowpack += snow;
                    const float melt = fminf(meltcap, snowpack);
                    meltwater += melt;
                    snowpack  -= melt;
                    const float refreeze = fminf(refcap, meltwater);
                    meltwater -= refreeze;
                    snowpack  += refreeze;
                    const float tosoil = fmaxf(fmaf(-cwh, snowpack, meltwater), 0.0f);
                    meltwater -= tosoil;
                    rtw[j * 64] = rain + tosoil;
                }
            }
        } else if (wid == 1) {
            // ---- soil-moisture chain, block i-1 ----
            const int b = i - 1;
            if (b >= 0 && b < NBLK) {
                const float* sb  = &s_stage[(b & 3) * SLOTD + (lane >> 2) * 3];
                const float* rtr = &s_rt[(b & 1) * RING + lane];
                float rt[BLK], ev[BLK], uum1[BLK];
                SCHED_FENCE();
                #pragma unroll
                for (int j = 0; j < BLK; ++j) { rt[j] = rtr[j * 64]; ev[j] = sb[j * SLOTW + 2]; }
                // off-chain VALU fills the read-latency shadow
                #pragma unroll
                for (int j = 0; j < BLK; ++j)
                    uum1[j] = fmaxf(fmaf(-ev[j], rlpfc, 1.0f), 0.0f);   // 1 - evap factor
                SCHED_FENCE();   // reads+uum1 stay above; chain runs on regs
                float* rexw = &s_rex[(b & 1) * RING + lane];
                #pragma unroll
                for (int j = 0; j < BLK; ++j) {
                    // sw = (sm/fc)^beta = exp2(beta*log2(sm) + beta*log2(1/fc))
                    const float sw    = __builtin_amdgcn_exp2f(fmaf(beta, __builtin_amdgcn_logf(sm), blfc));
                    const float smprt = sm + rt[j];
                    const float sm1   = fmaf(-rt[j], sw, smprt);   // sm + rt*(1-sw)
                    const float sm2   = fminf(sm1, fc);
                    // sm2 - min(sm2, sm2*uu, ev) = max(sm2*(1-uu), sm2-ev)
                    const float av = sm2 * uum1[j];
                    const float cv = sm2 - ev[j];
                    sm = fmaxf(fmaxf(av, cv), 1e-5f);              // v_max3
                    rexw[j * 64] = fmaf(rt[j], sw, sm1 - sm2);     // recharge + excess
                }
            }
        } else if (wid == 2) {
            // ---- response chain + quad mean, block i-2 ----
            const int b = i - 2;
            if (b >= 0 && b < NBLK) {
                const float* rexr = &s_rex[(b & 1) * RING + lane];
                float rex[BLK];
                SCHED_FENCE();
                #pragma unroll
                for (int j = 0; j < BLK; ++j) rex[j] = rexr[j * 64];
                SCHED_FENCE();
                float* qw = &s_q[(b & 1) * RING + lane];
                #pragma unroll
                for (int j = 0; j < BLK; ++j) {
                    const float suz1 = suz + rex[j];
                    const float prc  = fminf(suz1, perc);
                    const float suzA = suz1 - prc;
                    const float tq   = fmaxf(suzA - uzl, 0.0f);
                    const float q0   = k0 * tq;
                    const float suzB = fmaf(-k0, tq, suzA);
                    const float q1   = k1 * suzB;
                    suz = suzB * onemk1;
                    const float slz1 = slz + prc;
                    const float q2   = k2 * slz1;
                    slz = slz1 * onemk2;
                    qw[j * 64] = quad_sum(q0 + q1 + q2);   // *0.25 folded into w
                }
            }
        } else {
            // ---- 15-tap routing conv (gather form) + stores, block i-3 ----
            const int b = i - 3;
            if (b >= 0 && b < NBLK) {
                const int t0 = b * BLK;
                const float* qr = &s_q[(b & 1) * RING + lane];
                SCHED_FENCE();
                #pragma unroll
                for (int j = 0; j < BLK; ++j) qh[LENF - 1 + j] = qr[j * 64];
                SCHED_FENCE();
                float ov[(BLK + 3) / 4];
                #pragma unroll
                for (int k = 0; k < (BLK + 3) / 4; ++k) ov[k] = 0.0f;
                #pragma unroll
                for (int j = 0; j < BLK; ++j) {
                    float o = w[0] * qh[LENF - 1 + j];
                    #pragma unroll
                    for (int k = 1; k < LENF; ++k)
                        o = fmaf(w[k], qh[LENF - 1 + j - k], o);
                    const bool sel = ((j & 3) == m);
                    ov[j >> 2] = sel ? o : ov[j >> 2];     // j>>2 compile-time
                }
                #pragma unroll
                for (int d = 0; d < LENF - 1; ++d) qh[d] = qh[d + BLK];   // static shift
                #pragma unroll
                for (int k = 0; k < (BLK + 3) / 4; ++k) {
                    const int j = k * 4 + m;
                    const int t = t0 + j;
                    if (j < BLK && t >= WARM && t < TT)
                        out[(size_t)(t - WARM) * NG + g] = ov[k];
                }
            }
        }
        WG_BARRIER();
    }
    // drain wave0's leftover in-flight LDS-writing loads before endpgm
    if (wid == 0) asm volatile("s_waitcnt vmcnt(0)" ::: "memory");
}

extern "C" void kernel_launch(void* const* d_in, const int* in_sizes, int n_in,
                              void* d_out, int out_size, void* d_ws, size_t ws_size,
                              hipStream_t stream) {
    const float* xphy = (const float*)d_in[0];   // [2000, 4000, 3]
    const float* prm  = (const float*)d_in[1];   // [1, 4000, 50]
    float* out = (float*)d_out;                  // [1635, 4000, 1]

    hbv_pipe_kernel<<<NG / 16, 256, 0, stream>>>(xphy, prm, out);
}